// Round 3
// baseline (225.313 us; speedup 1.0000x reference)
//
#include <hip/hip_runtime.h>
#include <math.h>

// out = gamma * (S * x) + x  ==  (1 + gamma*S) * x
// S = (p+1)/(pi*(N-1)^2) * sum_{i,j in [0,N)} cos(q * atan2(j, i)),  p=2, q=1, N=256
// S is data-independent -> host constant. Streaming kernel, zero reuse ->
// nontemporal loads/stores (nt hint) to minimize L2 pollution.

typedef float v4f __attribute__((ext_vector_type(4)));  // clang vector: builtin-compatible

__global__ __launch_bounds__(256) void zam_scale_kernel(
    const v4f* __restrict__ x,
    const float* __restrict__ gamma,
    v4f* __restrict__ out,
    float S, int n4)
{
    // 2 x 16B per thread; grid exactly covers n4 (no tail at these sizes)
    int i0 = (blockIdx.x * blockDim.x + threadIdx.x) * 2;
    float scale = fmaf(gamma[0], S, 1.0f);

    if (i0 + 1 < n4) {
        v4f a = __builtin_nontemporal_load(&x[i0]);
        v4f b = __builtin_nontemporal_load(&x[i0 + 1]);
        a *= scale;
        b *= scale;
        __builtin_nontemporal_store(a, &out[i0]);
        __builtin_nontemporal_store(b, &out[i0 + 1]);
    } else if (i0 < n4) {
        v4f a = __builtin_nontemporal_load(&x[i0]);
        a *= scale;
        __builtin_nontemporal_store(a, &out[i0]);
    }
}

static float compute_S() {
    const int N = 256;
    const double p = 2.0, q = 1.0;
    double s = 0.0;
    for (int i = 0; i < N; ++i) {
        for (int j = 0; j < N; ++j) {
            s += cos(q * atan2((double)j, (double)i));  // atan2(0,0)==0, matches jnp
        }
    }
    return (float)(s * (p + 1.0) / (M_PI * (double)(N - 1) * (double)(N - 1)));
}

extern "C" void kernel_launch(void* const* d_in, const int* in_sizes, int n_in,
                              void* d_out, int out_size, void* d_ws, size_t ws_size,
                              hipStream_t stream) {
    const float* x     = (const float*)d_in[0];
    const float* gamma = (const float*)d_in[1];
    float* out         = (float*)d_out;

    static const float S = compute_S();  // deterministic host constant

    int n  = out_size;          // 33554432
    int n4 = n / 4;             // 8388608 float4s
    int per_block = 256 * 2;    // 2 x 16B per thread
    int grid = (n4 + per_block - 1) / per_block;  // 16384, no tail

    zam_scale_kernel<<<grid, 256, 0, stream>>>(
        (const v4f*)x, gamma, (v4f*)out, S, n4);
}